// Round 3
// baseline (399.951 us; speedup 1.0000x reference)
//
#include <hip/hip_runtime.h>

typedef short bf16x8 __attribute__((ext_vector_type(8)));
typedef float f32x4 __attribute__((ext_vector_type(4)));

#define AS1 __attribute__((address_space(1)))
#define AS3 __attribute__((address_space(3)))

__device__ __forceinline__ void gld16(void* lds, const void* g) {
  __builtin_amdgcn_global_load_lds((const AS1 unsigned int*)g,
                                   (AS3 unsigned int*)lds, 16, 0, 0);
}

__device__ __forceinline__ unsigned short f2bf(float f) {
  union { float f; unsigned int u; } c; c.f = f;
  return (unsigned short)((c.u + 0x7FFFu + ((c.u >> 16) & 1u)) >> 16);
}

// single-instruction RNE f32->bf16 (low half of v_cvt_pk result)
__device__ __forceinline__ unsigned short cvt1(float x) {
  unsigned int r;
  asm("v_cvt_pk_bf16_f32 %0, %1, %1" : "=v"(r) : "v"(x));
  return (unsigned short)r;
}

// ---------------- fp32 -> bf16 conversion ----------------
__global__ void cvt_kernel(const float4* __restrict__ in, ushort4* __restrict__ out, int n4) {
  int i = blockIdx.x * blockDim.x + threadIdx.x;
  int stride = gridDim.x * blockDim.x;
  for (; i < n4; i += stride) {
    float4 v = in[i];
    ushort4 o;
    o.x = f2bf(v.x); o.y = f2bf(v.y); o.z = f2bf(v.z); o.w = f2bf(v.w);
    out[i] = o;
  }
}

// all four 1024x1024 weights in one dispatch (blockIdx.y selects)
__global__ void cvtw_kernel(const float4* w0, const float4* w1,
                            const float4* w2, const float4* w3,
                            ushort4* o0, ushort4* o1, ushort4* o2, ushort4* o3,
                            int n4) {
  const float4* in; ushort4* out;
  switch (blockIdx.y) {
    case 0: in = w0; out = o0; break;
    case 1: in = w1; out = o1; break;
    case 2: in = w2; out = o2; break;
    default: in = w3; out = o3; break;
  }
  int i = blockIdx.x * blockDim.x + threadIdx.x;
  int stride = gridDim.x * blockDim.x;
  for (; i < n4; i += stride) {
    float4 v = in[i];
    ushort4 o;
    o.x = f2bf(v.x); o.y = f2bf(v.y); o.z = f2bf(v.z); o.w = f2bf(v.w);
    out[i] = o;
  }
}

// ---------------- NT GEMM: out[m][n] = (sum_k A[m][k]*W[n][k] + bias[n]) * scale ----
// 2-phase prefetch, double-buffered LDS. Optional second (W,bias,out) set
// selected when blockIdx.x >= splitX (fuses K and V projections).
__global__ __launch_bounds__(256) void gemm_bt_kernel(
    const unsigned short* __restrict__ A,
    const unsigned short* W,
    const float* bias,
    unsigned short* outB,               // bf16 output (or null)
    float* outF,                        // f32 output (or null)
    const unsigned short* W2,
    const float* bias2,
    unsigned short* outB2,
    int M, int N, int K, float scale, int splitX)
{
  __shared__ alignas(16) unsigned short As[2][4 * 128 * 8];
  __shared__ alignas(16) unsigned short Bs[2][4 * 128 * 8];

  int bx = blockIdx.x;
  if (bx >= splitX) { W = W2; bias = bias2; outB = outB2; bx -= splitX; }

  const int tid = threadIdx.x;
  const int lane = tid & 63;
  const int w = tid >> 6;
  const int wr = (w >> 1) * 64;
  const int wc = (w & 1) * 64;
  const int lrow = lane & 15;
  const int lk = lane >> 4;
  const long m0 = (long)blockIdx.y * 128;
  const long n0 = (long)bx * 128;

  f32x4 acc[4][4] = {};

  const int c0 = tid, c1 = tid + 256;
  const unsigned short* Ag0 = A + (m0 + (c0 & 127)) * (long)K + (c0 >> 7) * 8;
  const unsigned short* Ag1 = A + (m0 + (c1 & 127)) * (long)K + (c1 >> 7) * 8;
  const unsigned short* Wg0 = W + (n0 + (c0 & 127)) * (long)K + (c0 >> 7) * 8;
  const unsigned short* Wg1 = W + (n0 + (c1 & 127)) * (long)K + (c1 >> 7) * 8;

  const int arow = wr + lrow;
  const int brow = wc + lrow;
  const int nt = K >> 5;

  gld16(As[0] + c0 * 8, Ag0);
  gld16(As[0] + c1 * 8, Ag1);
  gld16(Bs[0] + c0 * 8, Wg0);
  gld16(Bs[0] + c1 * 8, Wg1);

  int cur = 0;
  for (int t = 0; t < nt; ++t) {
    __syncthreads();
    if (t + 1 < nt) {
      const int kt = (t + 1) * 32;
      gld16(As[cur ^ 1] + c0 * 8, Ag0 + kt);
      gld16(As[cur ^ 1] + c1 * 8, Ag1 + kt);
      gld16(Bs[cur ^ 1] + c0 * 8, Wg0 + kt);
      gld16(Bs[cur ^ 1] + c1 * 8, Wg1 + kt);
    }
    const unsigned short* as = As[cur];
    const unsigned short* bs = Bs[cur];
    bf16x8 af[4], bfr[4];
#pragma unroll
    for (int i = 0; i < 4; ++i)
      af[i] = *(const bf16x8*)(as + (lk * 128 + arow + i * 16) * 8);
#pragma unroll
    for (int j = 0; j < 4; ++j)
      bfr[j] = *(const bf16x8*)(bs + (lk * 128 + brow + j * 16) * 8);
#pragma unroll
    for (int i = 0; i < 4; ++i)
#pragma unroll
      for (int j = 0; j < 4; ++j)
        acc[i][j] = __builtin_amdgcn_mfma_f32_16x16x32_bf16(af[i], bfr[j], acc[i][j], 0, 0, 0);
    cur ^= 1;
  }

#pragma unroll
  for (int j = 0; j < 4; ++j) {
    const long col = n0 + wc + j * 16 + lrow;
    const float bv = bias[col];
#pragma unroll
    for (int i = 0; i < 4; ++i) {
#pragma unroll
      for (int r = 0; r < 4; ++r) {
        const long row = m0 + wr + i * 16 + lk * 4 + r;
        float v = (acc[i][j][r] + bv) * scale;
        if (outF) outF[row * (long)N + col] = v;
        else      outB[row * (long)N + col] = f2bf(v);
      }
    }
  }
}

// ---------------- Flash attention ----------------
// Q pre-scaled by 0.125*log2(e); softmax in exp2 domain. One barrier/tile:
// Ks and Vt double-buffered, Ps wave-private. Defer-max (THR=8).
__device__ __forceinline__ int vt_off(int d, int t) {
  const int c = (d ^ (d >> 3)) & 7;
  return d * 64 + (((((t >> 3) ^ c) & 7) << 3) | (t & 7));
}
__device__ __forceinline__ int ps_off(int q, int t) {
  return q * 64 + (((((t >> 3) ^ q) & 7) << 3) | (t & 7));
}

__global__ __launch_bounds__(256) void attn_kernel(
    const unsigned short* __restrict__ Q,
    const unsigned short* __restrict__ K,
    const unsigned short* __restrict__ V,
    unsigned short* __restrict__ Y)
{
  __shared__ alignas(16) unsigned short Ks[2][8 * 64 * 8];  // [buf][dblk][t][8] linear
  __shared__ alignas(16) unsigned short Vt[2][64 * 64];     // [buf][d][t] swizzled
  __shared__ alignas(16) unsigned short Ps[64 * 64];        // [q][t] swizzled, wave-private rows

  const int tid = threadIdx.x;
  const int lane = tid & 63;
  const int w = tid >> 6;
  const int lrow = lane & 15;
  const int lk = lane >> 4;
  const int b = blockIdx.z, h = blockIdx.y, qt = blockIdx.x;
  const long C = 1024, T = 2048, NQ = 2048;

  const unsigned short* Qg = Q + ((long)b * NQ + qt * 64) * C + h * 64;
  const unsigned short* Kg0 = K + (long)b * T * C + h * 64;
  const unsigned short* Vg0 = V + (long)b * T * C + h * 64;

  // prologue: stage K(0), Vt(0)
  {
    int c = tid;
    gld16(Ks[0] + c * 8, Kg0 + (long)(c & 63) * C + (c >> 6) * 8);
    c = tid + 256;
    gld16(Ks[0] + c * 8, Kg0 + (long)(c & 63) * C + (c >> 6) * 8);
  }
  bf16x8 qf[2];
#pragma unroll
  for (int kk = 0; kk < 2; ++kk)
    qf[kk] = *(const bf16x8*)(Qg + (long)(w * 16 + lrow) * C + (kk * 4 + lk) * 8);

  const int vrow = tid >> 2;            // t within tile
  const int vseg = (tid & 3) * 16;      // d base
  {
    const unsigned short* vgp = Vg0 + (long)vrow * C + vseg;
    bf16x8 v0 = *(const bf16x8*)(vgp);
    bf16x8 v1 = *(const bf16x8*)(vgp + 8);
    unsigned short* vt = Vt[0];
#pragma unroll
    for (int i = 0; i < 8; ++i) vt[vt_off(vseg + i, vrow)] = (unsigned short)v0[i];
#pragma unroll
    for (int i = 0; i < 8; ++i) vt[vt_off(vseg + 8 + i, vrow)] = (unsigned short)v1[i];
  }
  __syncthreads();

  f32x4 o[4] = {};
  float mr[4], lr[4];
#pragma unroll
  for (int r = 0; r < 4; ++r) { mr[r] = -1e30f; lr[r] = 0.f; }
  int cur = 0;

  const int paq = w * 16 + lrow;

  for (int kt = 0; kt < (int)T; kt += 64) {
    const bool more = (kt + 64 < (int)T);
    // prefetch next tile: K via gld16 into other buffer, V into regs
    bf16x8 nv0, nv1;
    if (more) {
      int c = tid;
      gld16(Ks[cur ^ 1] + c * 8, Kg0 + (long)(kt + 64 + (c & 63)) * C + (c >> 6) * 8);
      c = tid + 256;
      gld16(Ks[cur ^ 1] + c * 8, Kg0 + (long)(kt + 64 + (c & 63)) * C + (c >> 6) * 8);
      const unsigned short* vgn = Vg0 + (long)(kt + 64 + vrow) * C + vseg;
      nv0 = *(const bf16x8*)(vgn);
      nv1 = *(const bf16x8*)(vgn + 8);
    }

    // ---- S = Q K^T (log2-domain: scale*log2e folded into Q) ----
    f32x4 s[4] = {};
    __builtin_amdgcn_s_setprio(1);
#pragma unroll
    for (int kk = 0; kk < 2; ++kk) {
#pragma unroll
      for (int j = 0; j < 4; ++j) {
        bf16x8 kf = *(const bf16x8*)(Ks[cur] + ((kk * 4 + lk) * 64 + j * 16 + lrow) * 8);
        s[j] = __builtin_amdgcn_mfma_f32_16x16x32_bf16(qf[kk], kf, s[j], 0, 0, 0);
      }
    }
    __builtin_amdgcn_s_setprio(0);

    // ---- in-register online softmax (exp2 domain, defer-max) ----
    float pmax[4];
#pragma unroll
    for (int r = 0; r < 4; ++r) {
      float m = fmaxf(fmaxf(s[0][r], s[1][r]), fmaxf(s[2][r], s[3][r]));
      m = fmaxf(m, __shfl_xor(m, 1));
      m = fmaxf(m, __shfl_xor(m, 2));
      m = fmaxf(m, __shfl_xor(m, 4));
      m = fmaxf(m, __shfl_xor(m, 8));
      pmax[r] = m;
    }
    float dm = fmaxf(fmaxf(pmax[0] - mr[0], pmax[1] - mr[1]),
                     fmaxf(pmax[2] - mr[2], pmax[3] - mr[3]));
    if (__any(dm > 8.0f)) {
      // full rescale path
#pragma unroll
      for (int r = 0; r < 4; ++r) {
        const float mn = fmaxf(mr[r], pmax[r]);
        const float al = __builtin_amdgcn_exp2f(mr[r] - mn);
        mr[r] = mn;
        lr[r] *= al;
#pragma unroll
        for (int j = 0; j < 4; ++j) o[j][r] *= al;
      }
    }
#pragma unroll
    for (int r = 0; r < 4; ++r) {
      const int q = w * 16 + lk * 4 + r;
      float ls = 0.f;
#pragma unroll
      for (int j = 0; j < 4; ++j) {
        float p = __builtin_amdgcn_exp2f(s[j][r] - mr[r]);
        ls += p;
        Ps[ps_off(q, j * 16 + lrow)] = cvt1(p);
      }
      lr[r] += ls;  // lane-partial; reduced in epilogue
    }

    // ---- O += P V (Ps wave-private: no barrier needed) ----
    const unsigned short* vt = Vt[cur];
    __builtin_amdgcn_s_setprio(1);
#pragma unroll
    for (int kk = 0; kk < 2; ++kk) {
      const int tb = kk * 4 + lk;
      bf16x8 pa = *(const bf16x8*)(Ps + paq * 64 + (((tb ^ paq) & 7) << 3));
#pragma unroll
      for (int j = 0; j < 4; ++j) {
        const int d = j * 16 + lrow;
        const int cs = (d ^ (d >> 3)) & 7;
        bf16x8 vb = *(const bf16x8*)(vt + d * 64 + (((tb ^ cs) & 7) << 3));
        o[j] = __builtin_amdgcn_mfma_f32_16x16x32_bf16(pa, vb, o[j], 0, 0, 0);
      }
    }
    __builtin_amdgcn_s_setprio(0);

    // ---- write next V tile into the other Vt buffer ----
    if (more) {
      unsigned short* vtn = Vt[cur ^ 1];
#pragma unroll
      for (int i = 0; i < 8; ++i) vtn[vt_off(vseg + i, vrow)] = (unsigned short)nv0[i];
#pragma unroll
      for (int i = 0; i < 8; ++i) vtn[vt_off(vseg + 8 + i, vrow)] = (unsigned short)nv1[i];
    }
    cur ^= 1;
    __syncthreads();  // single barrier: drains gld16 (K next) + orders Vt/Ks buffers
  }

  // ---- epilogue ----
  unsigned short* Yg = Y + ((long)b * NQ + qt * 64) * C + h * 64;
  float linv[4];
#pragma unroll
  for (int r = 0; r < 4; ++r) {
    float l = lr[r];
    l += __shfl_xor(l, 1);
    l += __shfl_xor(l, 2);
    l += __shfl_xor(l, 4);
    l += __shfl_xor(l, 8);
    linv[r] = 1.f / l;
  }
#pragma unroll
  for (int j = 0; j < 4; ++j)
#pragma unroll
    for (int r = 0; r < 4; ++r) {
      const int row = w * 16 + lk * 4 + r;
      Yg[(long)row * C + j * 16 + lrow] = f2bf(o[j][r] * linv[r]);
    }
}

// ---------------- launcher ----------------
extern "C" void kernel_launch(void* const* d_in, const int* in_sizes, int n_in,
                              void* d_out, int out_size, void* d_ws, size_t ws_size,
                              hipStream_t stream) {
  (void)in_sizes; (void)n_in; (void)out_size; (void)ws_size;
  const float* x   = (const float*)d_in[0];
  const float* enc = (const float*)d_in[1];
  const float* Wq  = (const float*)d_in[2];
  const float* bq  = (const float*)d_in[3];
  const float* Wk  = (const float*)d_in[4];
  const float* bk  = (const float*)d_in[5];
  const float* Wv  = (const float*)d_in[6];
  const float* bv  = (const float*)d_in[7];
  const float* Wp  = (const float*)d_in[8];
  const float* bp  = (const float*)d_in[9];

  const long M = 4L * 2048;
  const long C = 1024;

  char* ws = (char*)d_ws;
  size_t off = 0;
  auto alloc = [&](size_t bytes) {
    char* p = ws + off;
    off += (bytes + 255) & ~(size_t)255;
    return p;
  };
  unsigned short* Xb  = (unsigned short*)alloc(M * C * 2);
  unsigned short* Eb  = (unsigned short*)alloc(M * C * 2);
  unsigned short* Wqb = (unsigned short*)alloc(C * C * 2);
  unsigned short* Wkb = (unsigned short*)alloc(C * C * 2);
  unsigned short* Wvb = (unsigned short*)alloc(C * C * 2);
  unsigned short* Wpb = (unsigned short*)alloc(C * C * 2);
  unsigned short* Qw  = (unsigned short*)alloc(M * C * 2);
  unsigned short* Kw  = (unsigned short*)alloc(M * C * 2);
  unsigned short* Vw  = (unsigned short*)alloc(M * C * 2);
  unsigned short* Yb  = (unsigned short*)alloc(M * C * 2);

  {
    int n4 = (int)(M * C / 4);
    int blocks = (n4 + 255) / 256; if (blocks > 2048) blocks = 2048;
    cvt_kernel<<<blocks, 256, 0, stream>>>((const float4*)x,   (ushort4*)Xb, n4);
    cvt_kernel<<<blocks, 256, 0, stream>>>((const float4*)enc, (ushort4*)Eb, n4);
    int w4 = (int)(C * C / 4);
    cvtw_kernel<<<dim3(1024, 4), 256, 0, stream>>>(
        (const float4*)Wq, (const float4*)Wk, (const float4*)Wv, (const float4*)Wp,
        (ushort4*)Wqb, (ushort4*)Wkb, (ushort4*)Wvb, (ushort4*)Wpb, w4);
  }

  // Q = (x Wq^T + bq) * (1/8)*log2(e)   (softmax runs in exp2 domain)
  const float qscale = 0.125f * 1.44269504088896f;
  gemm_bt_kernel<<<dim3(8, 64), 256, 0, stream>>>(
      Xb, Wqb, bq, Qw, nullptr, nullptr, nullptr, nullptr,
      (int)M, (int)C, (int)C, qscale, 999);
  // K and V fused in one dispatch
  gemm_bt_kernel<<<dim3(16, 64), 256, 0, stream>>>(
      Eb, Wkb, bk, Kw, nullptr, Wvb, bv, Vw,
      (int)M, (int)C, (int)C, 1.0f, 8);

  attn_kernel<<<dim3(32, 16, 4), 256, 0, stream>>>(Qw, Kw, Vw, Yb);

  gemm_bt_kernel<<<dim3(8, 64), 256, 0, stream>>>(
      Yb, Wpb, bp, nullptr, (float*)d_out, nullptr, nullptr, nullptr,
      (int)M, (int)C, (int)C, 1.0f, 999);
}

// Round 4
// 355.126 us; speedup vs baseline: 1.1262x; 1.1262x over previous
//
#include <hip/hip_runtime.h>

typedef short bf16x8 __attribute__((ext_vector_type(8)));
typedef float f32x4 __attribute__((ext_vector_type(4)));
typedef unsigned int u32x2 __attribute__((ext_vector_type(2)));

#define AS1 __attribute__((address_space(1)))
#define AS3 __attribute__((address_space(3)))

__device__ __forceinline__ void gld16(void* lds, const void* g) {
  __builtin_amdgcn_global_load_lds((const AS1 unsigned int*)g,
                                   (AS3 unsigned int*)lds, 16, 0, 0);
}

__device__ __forceinline__ unsigned short f2bf(float f) {
  union { float f; unsigned int u; } c; c.f = f;
  return (unsigned short)((c.u + 0x7FFFu + ((c.u >> 16) & 1u)) >> 16);
}

// packed RNE f32x2 -> bf16x2 in one instr
__device__ __forceinline__ unsigned int cvtpk(float lo, float hi) {
  unsigned int r;
  asm("v_cvt_pk_bf16_f32 %0, %1, %2" : "=v"(r) : "v"(lo), "v"(hi));
  return r;
}

// ---------------- fp32 -> bf16 conversion ----------------
__global__ void cvt_kernel(const float4* __restrict__ in, ushort4* __restrict__ out, int n4) {
  int i = blockIdx.x * blockDim.x + threadIdx.x;
  int stride = gridDim.x * blockDim.x;
  for (; i < n4; i += stride) {
    float4 v = in[i];
    ushort4 o;
    o.x = f2bf(v.x); o.y = f2bf(v.y); o.z = f2bf(v.z); o.w = f2bf(v.w);
    out[i] = o;
  }
}

// all four 1024x1024 weights in one dispatch (blockIdx.y selects)
__global__ void cvtw_kernel(const float4* w0, const float4* w1,
                            const float4* w2, const float4* w3,
                            ushort4* o0, ushort4* o1, ushort4* o2, ushort4* o3,
                            int n4) {
  const float4* in; ushort4* out;
  switch (blockIdx.y) {
    case 0: in = w0; out = o0; break;
    case 1: in = w1; out = o1; break;
    case 2: in = w2; out = o2; break;
    default: in = w3; out = o3; break;
  }
  int i = blockIdx.x * blockDim.x + threadIdx.x;
  int stride = gridDim.x * blockDim.x;
  for (; i < n4; i += stride) {
    float4 v = in[i];
    ushort4 o;
    o.x = f2bf(v.x); o.y = f2bf(v.y); o.z = f2bf(v.z); o.w = f2bf(v.w);
    out[i] = o;
  }
}

// ---------------- NT GEMM: out[m][n] = (sum_k A[m][k]*W[n][k] + bias[n]) * scale ----
__global__ __launch_bounds__(256) void gemm_bt_kernel(
    const unsigned short* __restrict__ A,
    const unsigned short* W,
    const float* bias,
    unsigned short* outB,
    float* outF,
    const unsigned short* W2,
    const float* bias2,
    unsigned short* outB2,
    int M, int N, int K, float scale, int splitX)
{
  __shared__ alignas(16) unsigned short As[2][4 * 128 * 8];
  __shared__ alignas(16) unsigned short Bs[2][4 * 128 * 8];

  int bx = blockIdx.x;
  if (bx >= splitX) { W = W2; bias = bias2; outB = outB2; bx -= splitX; }

  const int tid = threadIdx.x;
  const int lane = tid & 63;
  const int w = tid >> 6;
  const int wr = (w >> 1) * 64;
  const int wc = (w & 1) * 64;
  const int lrow = lane & 15;
  const int lk = lane >> 4;
  const long m0 = (long)blockIdx.y * 128;
  const long n0 = (long)bx * 128;

  f32x4 acc[4][4] = {};

  const int c0 = tid, c1 = tid + 256;
  const unsigned short* Ag0 = A + (m0 + (c0 & 127)) * (long)K + (c0 >> 7) * 8;
  const unsigned short* Ag1 = A + (m0 + (c1 & 127)) * (long)K + (c1 >> 7) * 8;
  const unsigned short* Wg0 = W + (n0 + (c0 & 127)) * (long)K + (c0 >> 7) * 8;
  const unsigned short* Wg1 = W + (n0 + (c1 & 127)) * (long)K + (c1 >> 7) * 8;

  const int arow = wr + lrow;
  const int brow = wc + lrow;
  const int nt = K >> 5;

  gld16(As[0] + c0 * 8, Ag0);
  gld16(As[0] + c1 * 8, Ag1);
  gld16(Bs[0] + c0 * 8, Wg0);
  gld16(Bs[0] + c1 * 8, Wg1);

  int cur = 0;
  for (int t = 0; t < nt; ++t) {
    __syncthreads();
    if (t + 1 < nt) {
      const int kt = (t + 1) * 32;
      gld16(As[cur ^ 1] + c0 * 8, Ag0 + kt);
      gld16(As[cur ^ 1] + c1 * 8, Ag1 + kt);
      gld16(Bs[cur ^ 1] + c0 * 8, Wg0 + kt);
      gld16(Bs[cur ^ 1] + c1 * 8, Wg1 + kt);
    }
    const unsigned short* as = As[cur];
    const unsigned short* bs = Bs[cur];
    bf16x8 af[4], bfr[4];
#pragma unroll
    for (int i = 0; i < 4; ++i)
      af[i] = *(const bf16x8*)(as + (lk * 128 + arow + i * 16) * 8);
#pragma unroll
    for (int j = 0; j < 4; ++j)
      bfr[j] = *(const bf16x8*)(bs + (lk * 128 + brow + j * 16) * 8);
#pragma unroll
    for (int i = 0; i < 4; ++i)
#pragma unroll
      for (int j = 0; j < 4; ++j)
        acc[i][j] = __builtin_amdgcn_mfma_f32_16x16x32_bf16(af[i], bfr[j], acc[i][j], 0, 0, 0);
    cur ^= 1;
  }

#pragma unroll
  for (int j = 0; j < 4; ++j) {
    const long col = n0 + wc + j * 16 + lrow;
    const float bv = bias[col];
#pragma unroll
    for (int i = 0; i < 4; ++i) {
#pragma unroll
      for (int r = 0; r < 4; ++r) {
        const long row = m0 + wr + i * 16 + lk * 4 + r;
        float v = (acc[i][j][r] + bv) * scale;
        if (outF) outF[row * (long)N + col] = v;
        else      outB[row * (long)N + col] = f2bf(v);
      }
    }
  }
}

// ---------------- Flash attention (swapped-operand S^T structure) ----------------
// Q pre-scaled by 0.125*log2(e). S^T = mfma(K,Q): lane owns q = w*16+(lane&15),
// t = j*16+lk*4+r -> softmax is lane-local (2 shfl per tile). PV swapped:
// O^T[d][q] = mfma(V^T, P) -> alpha/linv are per-lane scalars.
__device__ __forceinline__ int vt_off(int d, int t) {
  const int c = (d ^ (d >> 3)) & 7;
  return d * 64 + (((((t >> 3) ^ c) & 7) << 3) | (t & 7));
}

__global__ __launch_bounds__(256) void attn_kernel(
    const unsigned short* __restrict__ Q,
    const unsigned short* __restrict__ K,
    const unsigned short* __restrict__ V,
    unsigned short* __restrict__ Y)
{
  __shared__ alignas(16) unsigned short Ks[2][8 * 64 * 8];  // [buf][dblk][t][8] linear
  __shared__ alignas(16) unsigned short Vt[2][64 * 64];     // [buf][d][t] swizzled
  __shared__ alignas(16) unsigned short Ps[64 * 72];        // [q][t] stride-72, wave-private rows

  const int tid = threadIdx.x;
  const int lane = tid & 63;
  const int w = tid >> 6;
  const int lrow = lane & 15;
  const int lk = lane >> 4;

  // XCD-aware decode: id = (bh&7) + 8*(qt + 32*(bh>>3))
  const int id = blockIdx.x;
  const int r8 = id & 7;
  const int s5 = id >> 3;
  const int qt = s5 & 31;
  const int bh = r8 + 8 * (s5 >> 5);
  const int h = bh & 15, b = bh >> 4;
  const long C = 1024, T = 2048, NQ = 2048;

  const unsigned short* Qg = Q + ((long)b * NQ + qt * 64) * C + h * 64;
  const unsigned short* Kg0 = K + (long)b * T * C + h * 64;
  const unsigned short* Vg0 = V + (long)b * T * C + h * 64;

  // prologue: stage K(0), Vt(0)
  {
    int c = tid;
    gld16(Ks[0] + c * 8, Kg0 + (long)(c & 63) * C + (c >> 6) * 8);
    c = tid + 256;
    gld16(Ks[0] + c * 8, Kg0 + (long)(c & 63) * C + (c >> 6) * 8);
  }
  bf16x8 qf[2];
#pragma unroll
  for (int kk = 0; kk < 2; ++kk)
    qf[kk] = *(const bf16x8*)(Qg + (long)(w * 16 + lrow) * C + (kk * 4 + lk) * 8);

  const int vrow = tid >> 2;            // t within tile
  const int vseg = (tid & 3) * 16;      // d base
  {
    const unsigned short* vgp = Vg0 + (long)vrow * C + vseg;
    bf16x8 v0 = *(const bf16x8*)(vgp);
    bf16x8 v1 = *(const bf16x8*)(vgp + 8);
    unsigned short* vt = Vt[0];
#pragma unroll
    for (int i = 0; i < 8; ++i) vt[vt_off(vseg + i, vrow)] = (unsigned short)v0[i];
#pragma unroll
    for (int i = 0; i < 8; ++i) vt[vt_off(vseg + 8 + i, vrow)] = (unsigned short)v1[i];
  }
  __syncthreads();

  f32x4 o[4] = {};            // o[j][r]: d = j*16+lk*4+r, q = w*16+lrow
  float mr = -1e30f, lr = 0.f;
  int cur = 0;

  for (int kt = 0; kt < (int)T; kt += 64) {
    const bool more = (kt + 64 < (int)T);
    bf16x8 nv0, nv1;
    if (more) {
      int c = tid;
      gld16(Ks[cur ^ 1] + c * 8, Kg0 + (long)(kt + 64 + (c & 63)) * C + (c >> 6) * 8);
      c = tid + 256;
      gld16(Ks[cur ^ 1] + c * 8, Kg0 + (long)(kt + 64 + (c & 63)) * C + (c >> 6) * 8);
      const unsigned short* vgn = Vg0 + (long)(kt + 64 + vrow) * C + vseg;
      nv0 = *(const bf16x8*)(vgn);
      nv1 = *(const bf16x8*)(vgn + 8);
    }

    // ---- S^T = K Q^T: s[j] rows t = j*16+lk*4+r, col q = w*16+lrow ----
    f32x4 s[4] = {};
    __builtin_amdgcn_s_setprio(1);
#pragma unroll
    for (int kk = 0; kk < 2; ++kk) {
#pragma unroll
      for (int j = 0; j < 4; ++j) {
        bf16x8 kf = *(const bf16x8*)(Ks[cur] + ((kk * 4 + lk) * 64 + j * 16 + lrow) * 8);
        s[j] = __builtin_amdgcn_mfma_f32_16x16x32_bf16(kf, qf[kk], s[j], 0, 0, 0);
      }
    }
    __builtin_amdgcn_s_setprio(0);

    // ---- lane-local online softmax (exp2 domain, defer-max) ----
    float pm;
    {
      float m0 = fmaxf(fmaxf(s[0][0], s[0][1]), fmaxf(s[0][2], s[0][3]));
      float m1 = fmaxf(fmaxf(s[1][0], s[1][1]), fmaxf(s[1][2], s[1][3]));
      float m2 = fmaxf(fmaxf(s[2][0], s[2][1]), fmaxf(s[2][2], s[2][3]));
      float m3 = fmaxf(fmaxf(s[3][0], s[3][1]), fmaxf(s[3][2], s[3][3]));
      pm = fmaxf(fmaxf(m0, m1), fmaxf(m2, m3));
      pm = fmaxf(pm, __shfl_xor(pm, 16));
      pm = fmaxf(pm, __shfl_xor(pm, 32));
    }
    if (__any(pm - mr > 8.0f)) {
      const float mn = fmaxf(mr, pm);
      const float al = __builtin_amdgcn_exp2f(mr - mn);
      mr = mn;
      lr *= al;
#pragma unroll
      for (int j = 0; j < 4; ++j)
#pragma unroll
        for (int r = 0; r < 4; ++r) o[j][r] *= al;
    }
    {
      const int q = w * 16 + lrow;
      float ls = 0.f;
#pragma unroll
      for (int j = 0; j < 4; ++j) {
        float p0 = __builtin_amdgcn_exp2f(s[j][0] - mr);
        float p1 = __builtin_amdgcn_exp2f(s[j][1] - mr);
        float p2 = __builtin_amdgcn_exp2f(s[j][2] - mr);
        float p3 = __builtin_amdgcn_exp2f(s[j][3] - mr);
        ls += (p0 + p1) + (p2 + p3);
        u32x2 pk;
        pk.x = cvtpk(p0, p1);
        pk.y = cvtpk(p2, p3);
        *(u32x2*)(Ps + q * 72 + j * 16 + lk * 4) = pk;   // t = j*16+lk*4..+3
      }
      lr += ls;
    }

    // ---- O^T += V^T P  (Ps rows wave-private: no barrier) ----
    const unsigned short* vt = Vt[cur];
    __builtin_amdgcn_s_setprio(1);
#pragma unroll
    for (int kk = 0; kk < 2; ++kk) {
      bf16x8 pa = *(const bf16x8*)(Ps + (w * 16 + lrow) * 72 + kk * 32 + lk * 8);
#pragma unroll
      for (int j = 0; j < 4; ++j) {
        const int d = j * 16 + lrow;
        const int cs = (d ^ (d >> 3)) & 7;
        bf16x8 vb = *(const bf16x8*)(vt + d * 64 + ((((kk * 4 + lk) ^ cs) & 7) << 3));
        o[j] = __builtin_amdgcn_mfma_f32_16x16x32_bf16(vb, pa, o[j], 0, 0, 0);
      }
    }
    __builtin_amdgcn_s_setprio(0);

    if (more) {
      unsigned short* vtn = Vt[cur ^ 1];
#pragma unroll
      for (int i = 0; i < 8; ++i) vtn[vt_off(vseg + i, vrow)] = (unsigned short)nv0[i];
#pragma unroll
      for (int i = 0; i < 8; ++i) vtn[vt_off(vseg + 8 + i, vrow)] = (unsigned short)nv1[i];
    }
    cur ^= 1;
    __syncthreads();
  }

  // ---- epilogue: l across lk groups, normalize, packed 8B stores ----
  unsigned short* Yg = Y + ((long)b * NQ + qt * 64) * C + h * 64;
  float l = lr;
  l += __shfl_xor(l, 16);
  l += __shfl_xor(l, 32);
  const float linv = 1.f / l;
  const int q = w * 16 + lrow;
#pragma unroll
  for (int j = 0; j < 4; ++j) {
    u32x2 pk;
    pk.x = cvtpk(o[j][0] * linv, o[j][1] * linv);
    pk.y = cvtpk(o[j][2] * linv, o[j][3] * linv);
    *(u32x2*)(Yg + (long)q * C + j * 16 + lk * 4) = pk;
  }
}

// ---------------- launcher ----------------
extern "C" void kernel_launch(void* const* d_in, const int* in_sizes, int n_in,
                              void* d_out, int out_size, void* d_ws, size_t ws_size,
                              hipStream_t stream) {
  (void)in_sizes; (void)n_in; (void)out_size; (void)ws_size;
  const float* x   = (const float*)d_in[0];
  const float* enc = (const float*)d_in[1];
  const float* Wq  = (const float*)d_in[2];
  const float* bq  = (const float*)d_in[3];
  const float* Wk  = (const float*)d_in[4];
  const float* bk  = (const float*)d_in[5];
  const float* Wv  = (const float*)d_in[6];
  const float* bv  = (const float*)d_in[7];
  const float* Wp  = (const float*)d_in[8];
  const float* bp  = (const float*)d_in[9];

  const long M = 4L * 2048;
  const long C = 1024;

  char* ws = (char*)d_ws;
  size_t off = 0;
  auto alloc = [&](size_t bytes) {
    char* p = ws + off;
    off += (bytes + 255) & ~(size_t)255;
    return p;
  };
  unsigned short* Xb  = (unsigned short*)alloc(M * C * 2);
  unsigned short* Eb  = (unsigned short*)alloc(M * C * 2);
  unsigned short* Wqb = (unsigned short*)alloc(C * C * 2);
  unsigned short* Wkb = (unsigned short*)alloc(C * C * 2);
  unsigned short* Wvb = (unsigned short*)alloc(C * C * 2);
  unsigned short* Wpb = (unsigned short*)alloc(C * C * 2);
  unsigned short* Qw  = (unsigned short*)alloc(M * C * 2);
  unsigned short* Kw  = (unsigned short*)alloc(M * C * 2);
  unsigned short* Vw  = (unsigned short*)alloc(M * C * 2);
  unsigned short* Yb  = (unsigned short*)alloc(M * C * 2);

  {
    int n4 = (int)(M * C / 4);
    int blocks = (n4 + 255) / 256; if (blocks > 2048) blocks = 2048;
    cvt_kernel<<<blocks, 256, 0, stream>>>((const float4*)x,   (ushort4*)Xb, n4);
    cvt_kernel<<<blocks, 256, 0, stream>>>((const float4*)enc, (ushort4*)Eb, n4);
    int w4 = (int)(C * C / 4);
    cvtw_kernel<<<dim3(1024, 4), 256, 0, stream>>>(
        (const float4*)Wq, (const float4*)Wk, (const float4*)Wv, (const float4*)Wp,
        (ushort4*)Wqb, (ushort4*)Wkb, (ushort4*)Wvb, (ushort4*)Wpb, w4);
  }

  // Q = (x Wq^T + bq) * (1/8)*log2(e)   (softmax runs in exp2 domain)
  const float qscale = 0.125f * 1.44269504088896f;
  gemm_bt_kernel<<<dim3(8, 64), 256, 0, stream>>>(
      Xb, Wqb, bq, Qw, nullptr, nullptr, nullptr, nullptr,
      (int)M, (int)C, (int)C, qscale, 999);
  gemm_bt_kernel<<<dim3(16, 64), 256, 0, stream>>>(
      Eb, Wkb, bk, Kw, nullptr, Wvb, bv, Vw,
      (int)M, (int)C, (int)C, 1.0f, 8);

  attn_kernel<<<2048, 256, 0, stream>>>(Qw, Kw, Vw, Yb);

  gemm_bt_kernel<<<dim3(8, 64), 256, 0, stream>>>(
      Yb, Wpb, bp, nullptr, (float*)d_out, nullptr, nullptr, nullptr,
      (int)M, (int)C, (int)C, 1.0f, 999);
}

// Round 5
// 298.596 us; speedup vs baseline: 1.3394x; 1.1893x over previous
//
#include <hip/hip_runtime.h>

typedef short bf16x8 __attribute__((ext_vector_type(8)));
typedef float f32x4 __attribute__((ext_vector_type(4)));
typedef unsigned int u32x2 __attribute__((ext_vector_type(2)));

#define AS1 __attribute__((address_space(1)))
#define AS3 __attribute__((address_space(3)))

__device__ __forceinline__ void gld16(void* lds, const void* g) {
  __builtin_amdgcn_global_load_lds((const AS1 unsigned int*)g,
                                   (AS3 unsigned int*)lds, 16, 0, 0);
}

__device__ __forceinline__ unsigned short f2bf(float f) {
  union { float f; unsigned int u; } c; c.f = f;
  return (unsigned short)((c.u + 0x7FFFu + ((c.u >> 16) & 1u)) >> 16);
}

// packed RNE f32x2 -> bf16x2 in one instr
__device__ __forceinline__ unsigned int cvtpk(float lo, float hi) {
  unsigned int r;
  asm("v_cvt_pk_bf16_f32 %0, %1, %2" : "=v"(r) : "v"(lo), "v"(hi));
  return r;
}

// ---------------- fp32 -> bf16 conversion (x and enc fused via grid.y) ------
__global__ void cvt_kernel(const float4* __restrict__ in0,
                           const float4* __restrict__ in1,
                           ushort4* __restrict__ out0,
                           ushort4* __restrict__ out1, int n4) {
  const float4* in = blockIdx.y ? in1 : in0;
  ushort4* out = blockIdx.y ? out1 : out0;
  int i = blockIdx.x * blockDim.x + threadIdx.x;
  int stride = gridDim.x * blockDim.x;
  for (; i < n4; i += stride) {
    float4 v = in[i];
    ushort4 o;
    o.x = f2bf(v.x); o.y = f2bf(v.y); o.z = f2bf(v.z); o.w = f2bf(v.w);
    out[i] = o;
  }
}

// all four 1024x1024 weights in one dispatch (blockIdx.y selects)
__global__ void cvtw_kernel(const float4* w0, const float4* w1,
                            const float4* w2, const float4* w3,
                            ushort4* o0, ushort4* o1, ushort4* o2, ushort4* o3,
                            int n4) {
  const float4* in; ushort4* out;
  switch (blockIdx.y) {
    case 0: in = w0; out = o0; break;
    case 1: in = w1; out = o1; break;
    case 2: in = w2; out = o2; break;
    default: in = w3; out = o3; break;
  }
  int i = blockIdx.x * blockDim.x + threadIdx.x;
  int stride = gridDim.x * blockDim.x;
  for (; i < n4; i += stride) {
    float4 v = in[i];
    ushort4 o;
    o.x = f2bf(v.x); o.y = f2bf(v.y); o.z = f2bf(v.z); o.w = f2bf(v.w);
    out[i] = o;
  }
}

// ---------------- fused QKV projection GEMM --------------------------------
// grid (24, 64): sections of 8 x-blocks: 0=Q (bf16, *qscale), 1=K (bf16),
// 2=V written TRANSPOSED as V^T[1024 hd][8192 t] (swapped MFMA operands).
__global__ __launch_bounds__(256) void gemm_qkv_kernel(
    const unsigned short* __restrict__ Xb,
    const unsigned short* __restrict__ Eb,
    const unsigned short* __restrict__ Wqb,
    const unsigned short* __restrict__ Wkb,
    const unsigned short* __restrict__ Wvb,
    const float* __restrict__ bq,
    const float* __restrict__ bk,
    const float* __restrict__ bv,
    unsigned short* __restrict__ Qw,
    unsigned short* __restrict__ Kw,
    unsigned short* __restrict__ VTw,
    float qscale)
{
  __shared__ alignas(16) unsigned short As[2][4 * 128 * 8];
  __shared__ alignas(16) unsigned short Bs[2][4 * 128 * 8];

  const int sec = blockIdx.x >> 3;
  const int bx = blockIdx.x & 7;
  const unsigned short* A = (sec == 0) ? Xb : Eb;
  const unsigned short* W = (sec == 0) ? Wqb : (sec == 1) ? Wkb : Wvb;
  const float* bias = (sec == 0) ? bq : (sec == 1) ? bk : bv;

  const int K = 1024, N = 1024;
  const int tid = threadIdx.x;
  const int lane = tid & 63;
  const int w = tid >> 6;
  const int wr = (w >> 1) * 64;
  const int wc = (w & 1) * 64;
  const int lrow = lane & 15;
  const int lk = lane >> 4;
  const long m0 = (long)blockIdx.y * 128;
  const long n0 = (long)bx * 128;

  f32x4 acc[4][4] = {};

  const int c0 = tid, c1 = tid + 256;
  const unsigned short* Ag0 = A + (m0 + (c0 & 127)) * (long)K + (c0 >> 7) * 8;
  const unsigned short* Ag1 = A + (m0 + (c1 & 127)) * (long)K + (c1 >> 7) * 8;
  const unsigned short* Wg0 = W + (n0 + (c0 & 127)) * (long)K + (c0 >> 7) * 8;
  const unsigned short* Wg1 = W + (n0 + (c1 & 127)) * (long)K + (c1 >> 7) * 8;

  const int arow = wr + lrow;
  const int brow = wc + lrow;
  const int nt = K >> 5;

  gld16(As[0] + c0 * 8, Ag0);
  gld16(As[0] + c1 * 8, Ag1);
  gld16(Bs[0] + c0 * 8, Wg0);
  gld16(Bs[0] + c1 * 8, Wg1);

  int cur = 0;
  for (int t = 0; t < nt; ++t) {
    __syncthreads();
    if (t + 1 < nt) {
      const int kt = (t + 1) * 32;
      gld16(As[cur ^ 1] + c0 * 8, Ag0 + kt);
      gld16(As[cur ^ 1] + c1 * 8, Ag1 + kt);
      gld16(Bs[cur ^ 1] + c0 * 8, Wg0 + kt);
      gld16(Bs[cur ^ 1] + c1 * 8, Wg1 + kt);
    }
    const unsigned short* as = As[cur];
    const unsigned short* bs = Bs[cur];
    bf16x8 af[4], bfr[4];
#pragma unroll
    for (int i = 0; i < 4; ++i)
      af[i] = *(const bf16x8*)(as + (lk * 128 + arow + i * 16) * 8);
#pragma unroll
    for (int j = 0; j < 4; ++j)
      bfr[j] = *(const bf16x8*)(bs + (lk * 128 + brow + j * 16) * 8);
    if (sec != 2) {
#pragma unroll
      for (int i = 0; i < 4; ++i)
#pragma unroll
        for (int j = 0; j < 4; ++j)
          acc[i][j] = __builtin_amdgcn_mfma_f32_16x16x32_bf16(af[i], bfr[j], acc[i][j], 0, 0, 0);
    } else {
      // swapped: C[row = W-feature][col = t]
#pragma unroll
      for (int i = 0; i < 4; ++i)
#pragma unroll
        for (int j = 0; j < 4; ++j)
          acc[i][j] = __builtin_amdgcn_mfma_f32_16x16x32_bf16(bfr[i], af[j], acc[i][j], 0, 0, 0);
    }
    cur ^= 1;
  }

  if (sec != 2) {
    unsigned short* out = (sec == 0) ? Qw : Kw;
    const float scale = (sec == 0) ? qscale : 1.0f;
#pragma unroll
    for (int j = 0; j < 4; ++j) {
      const long col = n0 + wc + j * 16 + lrow;
      const float bv_ = bias[col];
#pragma unroll
      for (int i = 0; i < 4; ++i)
#pragma unroll
        for (int r = 0; r < 4; ++r) {
          const long row = m0 + wr + i * 16 + lk * 4 + r;
          out[row * (long)N + col] = f2bf((acc[i][j][r] + bv_) * scale);
        }
    }
  } else {
    // V^T: row = feature (n0 + wc + i*16 + lk*4 + r), col = t (m0 + wr + j*16 + lrow)
#pragma unroll
    for (int i = 0; i < 4; ++i)
#pragma unroll
      for (int r = 0; r < 4; ++r) {
        const long feat = n0 + wc + i * 16 + lk * 4 + r;
        const float bv_ = bias[feat];
#pragma unroll
        for (int j = 0; j < 4; ++j) {
          const long col = m0 + wr + j * 16 + lrow;
          VTw[feat * 8192 + col] = f2bf(acc[i][j][r] + bv_);
        }
      }
  }
}

// ---------------- plain NT GEMM for final projection (f32 out) -------------
__global__ __launch_bounds__(256) void gemm_bt_kernel(
    const unsigned short* __restrict__ A,
    const unsigned short* __restrict__ W,
    const float* __restrict__ bias,
    float* __restrict__ outF,
    int M, int N, int K)
{
  __shared__ alignas(16) unsigned short As[2][4 * 128 * 8];
  __shared__ alignas(16) unsigned short Bs[2][4 * 128 * 8];

  const int tid = threadIdx.x;
  const int lane = tid & 63;
  const int w = tid >> 6;
  const int wr = (w >> 1) * 64;
  const int wc = (w & 1) * 64;
  const int lrow = lane & 15;
  const int lk = lane >> 4;
  const long m0 = (long)blockIdx.y * 128;
  const long n0 = (long)blockIdx.x * 128;

  f32x4 acc[4][4] = {};

  const int c0 = tid, c1 = tid + 256;
  const unsigned short* Ag0 = A + (m0 + (c0 & 127)) * (long)K + (c0 >> 7) * 8;
  const unsigned short* Ag1 = A + (m0 + (c1 & 127)) * (long)K + (c1 >> 7) * 8;
  const unsigned short* Wg0 = W + (n0 + (c0 & 127)) * (long)K + (c0 >> 7) * 8;
  const unsigned short* Wg1 = W + (n0 + (c1 & 127)) * (long)K + (c1 >> 7) * 8;

  const int arow = wr + lrow;
  const int brow = wc + lrow;
  const int nt = K >> 5;

  gld16(As[0] + c0 * 8, Ag0);
  gld16(As[0] + c1 * 8, Ag1);
  gld16(Bs[0] + c0 * 8, Wg0);
  gld16(Bs[0] + c1 * 8, Wg1);

  int cur = 0;
  for (int t = 0; t < nt; ++t) {
    __syncthreads();
    if (t + 1 < nt) {
      const int kt = (t + 1) * 32;
      gld16(As[cur ^ 1] + c0 * 8, Ag0 + kt);
      gld16(As[cur ^ 1] + c1 * 8, Ag1 + kt);
      gld16(Bs[cur ^ 1] + c0 * 8, Wg0 + kt);
      gld16(Bs[cur ^ 1] + c1 * 8, Wg1 + kt);
    }
    const unsigned short* as = As[cur];
    const unsigned short* bs = Bs[cur];
    bf16x8 af[4], bfr[4];
#pragma unroll
    for (int i = 0; i < 4; ++i)
      af[i] = *(const bf16x8*)(as + (lk * 128 + arow + i * 16) * 8);
#pragma unroll
    for (int j = 0; j < 4; ++j)
      bfr[j] = *(const bf16x8*)(bs + (lk * 128 + brow + j * 16) * 8);
#pragma unroll
    for (int i = 0; i < 4; ++i)
#pragma unroll
      for (int j = 0; j < 4; ++j)
        acc[i][j] = __builtin_amdgcn_mfma_f32_16x16x32_bf16(af[i], bfr[j], acc[i][j], 0, 0, 0);
    cur ^= 1;
  }

#pragma unroll
  for (int j = 0; j < 4; ++j) {
    const long col = n0 + wc + j * 16 + lrow;
    const float bv_ = bias[col];
#pragma unroll
    for (int i = 0; i < 4; ++i)
#pragma unroll
      for (int r = 0; r < 4; ++r) {
        const long row = m0 + wr + i * 16 + lk * 4 + r;
        outF[row * (long)N + col] = acc[i][j][r] + bv_;
      }
  }
}

// ---------------- Flash attention (QBLK=128, V^T input) --------------------
// Q pre-scaled by 0.125*log2(e). S^T = mfma(K,Q): lane owns q = w*16+lrow+64f.
// V^T staged via gld16 with pre-swizzled source; l-sum via ones-MFMA.
__global__ __launch_bounds__(256) void attn_kernel(
    const unsigned short* __restrict__ Q,
    const unsigned short* __restrict__ K,
    const unsigned short* __restrict__ VT,
    unsigned short* __restrict__ Y)
{
  __shared__ alignas(16) unsigned short Ks[2][8 * 64 * 8];  // [buf][dblk][t][8] linear
  __shared__ alignas(16) unsigned short Vt[2][64 * 64];     // [buf][d][t] chunk-swizzled
  __shared__ alignas(16) unsigned short Ps[128 * 72];       // [q][t] stride-72, wave-private rows

  const int tid = threadIdx.x;
  const int lane = tid & 63;
  const int w = tid >> 6;
  const int lrow = lane & 15;
  const int lk = lane >> 4;

  // XCD-aware decode: 1024 blocks; id = (bh&7) + 8*(qt + 16*(bh>>3))
  const int id = blockIdx.x;
  const int r8 = id & 7;
  const int s5 = id >> 3;
  const int qt = s5 & 15;
  const int bh = r8 + 8 * (s5 >> 4);
  const int h = bh & 15, b = bh >> 4;
  const long C = 1024, T = 2048, NQ = 2048;

  const unsigned short* Qg = Q + ((long)b * NQ + qt * 128) * C + h * 64;
  const unsigned short* Kg0 = K + (long)b * T * C + h * 64;
  const unsigned short* Vg0 = VT + (long)(h * 64) * 8192 + b * 2048;  // rows d, stride 8192

  // prologue: stage K(0), V(0)
  {
    int c = tid;
    gld16(Ks[0] + c * 8, Kg0 + (long)(c & 63) * C + (c >> 6) * 8);
    c = tid + 256;
    gld16(Ks[0] + c * 8, Kg0 + (long)(c & 63) * C + (c >> 6) * 8);
    c = tid;
    gld16(Vt[0] + c * 8, Vg0 + (long)(c >> 3) * 8192 + (((c & 7) ^ ((c >> 3) & 7)) * 8));
    c = tid + 256;
    gld16(Vt[0] + c * 8, Vg0 + (long)(c >> 3) * 8192 + (((c & 7) ^ ((c >> 3) & 7)) * 8));
  }
  bf16x8 qf[2][2];
#pragma unroll
  for (int f = 0; f < 2; ++f)
#pragma unroll
    for (int kk = 0; kk < 2; ++kk)
      qf[f][kk] = *(const bf16x8*)(Qg + (long)(f * 64 + w * 16 + lrow) * C + (kk * 4 + lk) * 8);

  bf16x8 ones;
#pragma unroll
  for (int e = 0; e < 8; ++e) ones[e] = (short)0x3F80;

  __syncthreads();

  f32x4 oA[4] = {}, oB[4] = {};   // o[f][j][r]: d = j*16+lk*4+r, q = w*16+lrow+64f
  f32x4 olA = {}, olB = {};       // l accumulators (all rows identical)
  float mrA = -1e30f, mrB = -1e30f;
  int cur = 0;

  const int qrow0 = w * 16 + lrow;

  for (int kt = 0; kt < (int)T; kt += 64) {
    const bool more = (kt + 64 < (int)T);
    if (more) {
      int c = tid;
      gld16(Ks[cur ^ 1] + c * 8, Kg0 + (long)(kt + 64 + (c & 63)) * C + (c >> 6) * 8);
      gld16(Vt[cur ^ 1] + c * 8,
            Vg0 + (long)(c >> 3) * 8192 + kt + 64 + (((c & 7) ^ ((c >> 3) & 7)) * 8));
      c = tid + 256;
      gld16(Ks[cur ^ 1] + c * 8, Kg0 + (long)(kt + 64 + (c & 63)) * C + (c >> 6) * 8);
      gld16(Vt[cur ^ 1] + c * 8,
            Vg0 + (long)(c >> 3) * 8192 + kt + 64 + (((c & 7) ^ ((c >> 3) & 7)) * 8));
    }

    // ---- S^T = K Q^T for both q-halves ----
    f32x4 sA[4] = {}, sB[4] = {};
    __builtin_amdgcn_s_setprio(1);
#pragma unroll
    for (int kk = 0; kk < 2; ++kk) {
#pragma unroll
      for (int j = 0; j < 4; ++j) {
        bf16x8 kf = *(const bf16x8*)(Ks[cur] + ((kk * 4 + lk) * 64 + j * 16 + lrow) * 8);
        sA[j] = __builtin_amdgcn_mfma_f32_16x16x32_bf16(kf, qf[0][kk], sA[j], 0, 0, 0);
        sB[j] = __builtin_amdgcn_mfma_f32_16x16x32_bf16(kf, qf[1][kk], sB[j], 0, 0, 0);
      }
    }
    __builtin_amdgcn_s_setprio(0);

    // ---- lane-local online softmax (exp2 domain, defer-max) ----
    float pmA, pmB;
    {
      float a = fmaxf(fmaxf(fmaxf(sA[0][0], sA[0][1]), fmaxf(sA[0][2], sA[0][3])),
                      fmaxf(fmaxf(sA[1][0], sA[1][1]), fmaxf(sA[1][2], sA[1][3])));
      float b2 = fmaxf(fmaxf(fmaxf(sA[2][0], sA[2][1]), fmaxf(sA[2][2], sA[2][3])),
                       fmaxf(fmaxf(sA[3][0], sA[3][1]), fmaxf(sA[3][2], sA[3][3])));
      pmA = fmaxf(a, b2);
      pmA = fmaxf(pmA, __shfl_xor(pmA, 16));
      pmA = fmaxf(pmA, __shfl_xor(pmA, 32));
      float c2 = fmaxf(fmaxf(fmaxf(sB[0][0], sB[0][1]), fmaxf(sB[0][2], sB[0][3])),
                       fmaxf(fmaxf(sB[1][0], sB[1][1]), fmaxf(sB[1][2], sB[1][3])));
      float d2 = fmaxf(fmaxf(fmaxf(sB[2][0], sB[2][1]), fmaxf(sB[2][2], sB[2][3])),
                       fmaxf(fmaxf(sB[3][0], sB[3][1]), fmaxf(sB[3][2], sB[3][3])));
      pmB = fmaxf(c2, d2);
      pmB = fmaxf(pmB, __shfl_xor(pmB, 16));
      pmB = fmaxf(pmB, __shfl_xor(pmB, 32));
    }
    if (__any(fmaxf(pmA - mrA, pmB - mrB) > 8.0f)) {
      {
        const float mn = fmaxf(mrA, pmA);
        const float al = __builtin_amdgcn_exp2f(mrA - mn);
        mrA = mn; olA *= al;
#pragma unroll
        for (int j = 0; j < 4; ++j) oA[j] *= al;
      }
      {
        const float mn = fmaxf(mrB, pmB);
        const float al = __builtin_amdgcn_exp2f(mrB - mn);
        mrB = mn; olB *= al;
#pragma unroll
        for (int j = 0; j < 4; ++j) oB[j] *= al;
      }
    }
#pragma unroll
    for (int j = 0; j < 4; ++j) {
      float p0 = __builtin_amdgcn_exp2f(sA[j][0] - mrA);
      float p1 = __builtin_amdgcn_exp2f(sA[j][1] - mrA);
      float p2 = __builtin_amdgcn_exp2f(sA[j][2] - mrA);
      float p3 = __builtin_amdgcn_exp2f(sA[j][3] - mrA);
      u32x2 pk;
      pk.x = cvtpk(p0, p1);
      pk.y = cvtpk(p2, p3);
      *(u32x2*)(Ps + qrow0 * 72 + j * 16 + lk * 4) = pk;
    }
#pragma unroll
    for (int j = 0; j < 4; ++j) {
      float p0 = __builtin_amdgcn_exp2f(sB[j][0] - mrB);
      float p1 = __builtin_amdgcn_exp2f(sB[j][1] - mrB);
      float p2 = __builtin_amdgcn_exp2f(sB[j][2] - mrB);
      float p3 = __builtin_amdgcn_exp2f(sB[j][3] - mrB);
      u32x2 pk;
      pk.x = cvtpk(p0, p1);
      pk.y = cvtpk(p2, p3);
      *(u32x2*)(Ps + (64 + qrow0) * 72 + j * 16 + lk * 4) = pk;
    }

    // ---- O^T += V^T P ; l += 1^T P (Ps rows wave-private: no barrier) ----
    const unsigned short* vt = Vt[cur];
    __builtin_amdgcn_s_setprio(1);
#pragma unroll
    for (int kk = 0; kk < 2; ++kk) {
      bf16x8 pa0 = *(const bf16x8*)(Ps + qrow0 * 72 + kk * 32 + lk * 8);
      bf16x8 pa1 = *(const bf16x8*)(Ps + (64 + qrow0) * 72 + kk * 32 + lk * 8);
      olA = __builtin_amdgcn_mfma_f32_16x16x32_bf16(ones, pa0, olA, 0, 0, 0);
      olB = __builtin_amdgcn_mfma_f32_16x16x32_bf16(ones, pa1, olB, 0, 0, 0);
#pragma unroll
      for (int j = 0; j < 4; ++j) {
        const int d = j * 16 + lrow;
        bf16x8 vb = *(const bf16x8*)(vt + d * 64 + ((((kk * 4 + lk) ^ (d & 7)) & 7) << 3));
        oA[j] = __builtin_amdgcn_mfma_f32_16x16x32_bf16(vb, pa0, oA[j], 0, 0, 0);
        oB[j] = __builtin_amdgcn_mfma_f32_16x16x32_bf16(vb, pa1, oB[j], 0, 0, 0);
      }
    }
    __builtin_amdgcn_s_setprio(0);

    cur ^= 1;
    __syncthreads();  // drains gld16s; orders buffer reuse
  }

  // ---- epilogue: normalize (l from ones-MFMA, no cross-lane reduce) ----
  unsigned short* Yg = Y + ((long)b * NQ + qt * 128) * C + h * 64;
  const float linvA = 1.f / olA[0];
  const float linvB = 1.f / olB[0];
#pragma unroll
  for (int j = 0; j < 4; ++j) {
    u32x2 pk;
    pk.x = cvtpk(oA[j][0] * linvA, oA[j][1] * linvA);
    pk.y = cvtpk(oA[j][2] * linvA, oA[j][3] * linvA);
    *(u32x2*)(Yg + (long)qrow0 * C + j * 16 + lk * 4) = pk;
    pk.x = cvtpk(oB[j][0] * linvB, oB[j][1] * linvB);
    pk.y = cvtpk(oB[j][2] * linvB, oB[j][3] * linvB);
    *(u32x2*)(Yg + (long)(64 + qrow0) * C + j * 16 + lk * 4) = pk;
  }
}

// ---------------- launcher ----------------
extern "C" void kernel_launch(void* const* d_in, const int* in_sizes, int n_in,
                              void* d_out, int out_size, void* d_ws, size_t ws_size,
                              hipStream_t stream) {
  (void)in_sizes; (void)n_in; (void)out_size; (void)ws_size;
  const float* x   = (const float*)d_in[0];
  const float* enc = (const float*)d_in[1];
  const float* Wq  = (const float*)d_in[2];
  const float* bq  = (const float*)d_in[3];
  const float* Wk  = (const float*)d_in[4];
  const float* bk  = (const float*)d_in[5];
  const float* Wv  = (const float*)d_in[6];
  const float* bv  = (const float*)d_in[7];
  const float* Wp  = (const float*)d_in[8];
  const float* bp  = (const float*)d_in[9];

  const long M = 4L * 2048;
  const long C = 1024;

  char* ws = (char*)d_ws;
  size_t off = 0;
  auto alloc = [&](size_t bytes) {
    char* p = ws + off;
    off += (bytes + 255) & ~(size_t)255;
    return p;
  };
  unsigned short* Xb  = (unsigned short*)alloc(M * C * 2);
  unsigned short* Eb  = (unsigned short*)alloc(M * C * 2);
  unsigned short* Wqb = (unsigned short*)alloc(C * C * 2);
  unsigned short* Wkb = (unsigned short*)alloc(C * C * 2);
  unsigned short* Wvb = (unsigned short*)alloc(C * C * 2);
  unsigned short* Wpb = (unsigned short*)alloc(C * C * 2);
  unsigned short* Qw  = (unsigned short*)alloc(M * C * 2);
  unsigned short* Kw  = (unsigned short*)alloc(M * C * 2);
  unsigned short* VTw = (unsigned short*)alloc(M * C * 2);  // V^T [1024][8192]
  unsigned short* Yb  = (unsigned short*)alloc(M * C * 2);

  {
    int n4 = (int)(M * C / 4);
    int blocks = (n4 + 255) / 256; if (blocks > 2048) blocks = 2048;
    cvt_kernel<<<dim3(blocks, 2), 256, 0, stream>>>(
        (const float4*)x, (const float4*)enc, (ushort4*)Xb, (ushort4*)Eb, n4);
    int w4 = (int)(C * C / 4);
    cvtw_kernel<<<dim3(1024, 4), 256, 0, stream>>>(
        (const float4*)Wq, (const float4*)Wk, (const float4*)Wv, (const float4*)Wp,
        (ushort4*)Wqb, (ushort4*)Wkb, (ushort4*)Wvb, (ushort4*)Wpb, w4);
  }

  // Q/K/V in one dispatch; Q scaled by (1/8)*log2(e); V written transposed
  const float qscale = 0.125f * 1.44269504088896f;
  gemm_qkv_kernel<<<dim3(24, 64), 256, 0, stream>>>(
      Xb, Eb, Wqb, Wkb, Wvb, bq, bk, bv, Qw, Kw, VTw, qscale);

  attn_kernel<<<1024, 256, 0, stream>>>(Qw, Kw, VTw, Yb);

  gemm_bt_kernel<<<dim3(8, 64), 256, 0, stream>>>(
      Yb, Wpb, bp, (float*)d_out, (int)M, (int)C, (int)C);
}